// Round 9
// baseline (1910.747 us; speedup 1.0000x reference)
//
#include <hip/hip_runtime.h>
#include <hip/hip_bf16.h>
#include <cmath>

#define NQ 8192
#define EMB 64
#define KSPLIT 32
#define KCHUNK (NQ / KSPLIT)
#define TMAX 32
#define MSCALE 256.0f
#define MINV (1.0f / 256.0f)
#define SUBK 64
#define BPAD 72
#define NSUB (KCHUNK / SUBK)

typedef __bf16 bf16x8 __attribute__((ext_vector_type(8)));
typedef _Float16 f16x8 __attribute__((ext_vector_type(8)));
typedef float f32x4 __attribute__((ext_vector_type(4)));

// ---------------------------------------------------------------------------
// M fp32 -> fp16 (scaled by 256 to stay clear of fp16 subnormals)
__global__ __launch_bounds__(256) void k_conv(const float* __restrict__ M,
                                              _Float16* __restrict__ Mh, long n) {
    long i = ((long)blockIdx.x * 256 + threadIdx.x) * 8;
    const long stride = (long)gridDim.x * 256 * 8;
    for (; i < n; i += stride) {
        float4 f0 = *(const float4*)(M + i);
        float4 f1 = *(const float4*)(M + i + 4);
        f16x8 o;
        o[0] = (_Float16)(f0.x * MSCALE); o[1] = (_Float16)(f0.y * MSCALE);
        o[2] = (_Float16)(f0.z * MSCALE); o[3] = (_Float16)(f0.w * MSCALE);
        o[4] = (_Float16)(f1.x * MSCALE); o[5] = (_Float16)(f1.y * MSCALE);
        o[6] = (_Float16)(f1.z * MSCALE); o[7] = (_Float16)(f1.w * MSCALE);
        *(f16x8*)(Mh + i) = o;
    }
}

// ---------------------------------------------------------------------------
// v0 + hi/lo bf16 weight prep (B^T layouts)
__global__ __launch_bounds__(256) void k_wprep(
    const float* __restrict__ vi_w1, const float* __restrict__ vi_b1,
    const float* __restrict__ vi_w2, const float* __restrict__ vi_b2,
    const float* __restrict__ w1, const float* __restrict__ w2,
    const float* __restrict__ wih, const float* __restrict__ whh,
    float* __restrict__ v0,
    __bf16* __restrict__ w1h, __bf16* __restrict__ w1l,
    __bf16* __restrict__ w2h, __bf16* __restrict__ w2l,
    __bf16* __restrict__ wihH, __bf16* __restrict__ wihL,
    __bf16* __restrict__ whhH, __bf16* __restrict__ whhL) {
    __shared__ float h[EMB];
    const int t = threadIdx.x;
    if (t < EMB) h[t] = vi_w1[t] + vi_b1[t];
    __syncthreads();
    if (t < EMB) {
        float s = vi_b2[t];
        for (int i = 0; i < EMB; ++i) s += h[i] * vi_w2[i * EMB + t];
        v0[t] = s;
    }
    for (int i = t; i < EMB * EMB; i += 256) {
        const int r = i >> 6, c = i & 63;     // target [r][c] = B[out][k]
        float v;
        __bf16 hi;
        v = w1[c * EMB + r]; hi = (__bf16)v;                 // w1t[j][k]=w1[k][j]
        w1h[i] = hi; w1l[i] = (__bf16)(v - (float)hi);
        v = w2[c * EMB + r]; hi = (__bf16)v;
        w2h[i] = hi; w2l[i] = (__bf16)(v - (float)hi);
        v = wih[i]; hi = (__bf16)v;                          // (x@wih^T): B=wih
        wihH[i] = hi; wihL[i] = (__bf16)(v - (float)hi);
        v = whh[i]; hi = (__bf16)v;
        whhH[i] = hi; whhL[i] = (__bf16)(v - (float)hi);
    }
}

// Vt hi/lo [c][k] = fp16 split of v0[c]
__global__ __launch_bounds__(256) void k_fill(const float* __restrict__ v0,
                                              _Float16* __restrict__ Vh,
                                              _Float16* __restrict__ Vl) {
    const int c = blockIdx.x;
    const float v = v0[c];
    const _Float16 hi = (_Float16)v;
    const _Float16 lo = (_Float16)(v - (float)hi);
    f16x8 oh = {hi, hi, hi, hi, hi, hi, hi, hi};
    f16x8 ol = {lo, lo, lo, lo, lo, lo, lo, lo};
    for (int i = threadIdx.x; i < NQ / 8; i += 256) {
        *(f16x8*)(Vh + (long)c * NQ + (long)i * 8) = oh;
        *(f16x8*)(Vl + (long)c * NQ + (long)i * 8) = ol;
    }
}

// ---------------------------------------------------------------------------
// partials[ks][row][col] = sum_{k chunk} Mh[row][k] * (Vh+Vl)[col][k]
// 64 rows/wave (4 row-subtiles share each B fragment: 0.25 LDS-reads/MFMA),
// 256 rows/block, KSPLIT=32 -> grid 1024 = 4 blocks/CU (4 waves/SIMD).
// Combines R4's B-read amortization with R5's occupancy. A loads are JIT
// (no prefetch) to stay under the 128-VGPR cap; 4 waves/SIMD cover the L3
// latency. B hi/lo staged in LDS, double-buffered 64-k subchunks.
__global__ __launch_bounds__(256, 4) void k_gemm_big(
    const _Float16* __restrict__ A, const _Float16* __restrict__ Bh,
    const _Float16* __restrict__ Bl, float* __restrict__ P) {
    __shared__ _Float16 Bs[2][2][EMB][BPAD];
    const int ks   = blockIdx.x & (KSPLIT - 1);
    const int rt   = blockIdx.x / KSPLIT;
    const int t    = threadIdx.x;
    const int wave = t >> 6;
    const int lane = t & 63;
    const int l15  = lane & 15;
    const int kg   = lane >> 4;
    const int row0 = rt * 256 + wave * 64;
    const long kcb = (long)ks * KCHUNK;
    const _Float16* Ap0 = A + (long)(row0 + l15) * NQ + kcb + kg * 8;
    const _Float16* Ap1 = Ap0 + (long)16 * NQ;
    const _Float16* Ap2 = Ap0 + (long)32 * NQ;
    const _Float16* Ap3 = Ap0 + (long)48 * NQ;
    // staging: thread t covers col=t/4, k-window (t%4)*16 .. +16 of each subchunk
    const int scol  = t >> 2;
    const int spart = (t & 3) * 16;
    const _Float16* gH = Bh + (long)scol * NQ + kcb + spart;
    const _Float16* gL = Bl + (long)scol * NQ + kcb + spart;

    f32x4 acc00 = {}, acc01 = {}, acc02 = {}, acc03 = {};
    f32x4 acc10 = {}, acc11 = {}, acc12 = {}, acc13 = {};
    f32x4 acc20 = {}, acc21 = {}, acc22 = {}, acc23 = {};
    f32x4 acc30 = {}, acc31 = {}, acc32 = {}, acc33 = {};

    // prologue: stage subchunk 0 into buf 0
    f16x8 sh0 = *(const f16x8*)(gH);
    f16x8 sh1 = *(const f16x8*)(gH + 8);
    f16x8 sl0 = *(const f16x8*)(gL);
    f16x8 sl1 = *(const f16x8*)(gL + 8);
    *(f16x8*)&Bs[0][0][scol][spart]     = sh0;
    *(f16x8*)&Bs[0][0][scol][spart + 8] = sh1;
    *(f16x8*)&Bs[0][1][scol][spart]     = sl0;
    *(f16x8*)&Bs[0][1][scol][spart + 8] = sl1;
    __syncthreads();

#pragma unroll
    for (int sub = 0; sub < NSUB; ++sub) {   // 4 subchunks of 64 k
        const int buf = sub & 1;
        // prefetch next subchunk's B (global -> regs), LDS-write after compute
        if (sub < NSUB - 1) {
            const long nk = (long)(sub + 1) * SUBK;
            sh0 = *(const f16x8*)(gH + nk);
            sh1 = *(const f16x8*)(gH + nk + 8);
            sl0 = *(const f16x8*)(gL + nk);
            sl1 = *(const f16x8*)(gL + nk + 8);
        }
#pragma unroll
        for (int it = 0; it < 2; ++it) {      // 2 iters of k=32
            const long ka = (long)sub * SUBK + it * 32;
            const int  kl = it * 32 + kg * 8;
            f16x8 a0 = *(const f16x8*)(Ap0 + ka);
            f16x8 a1 = *(const f16x8*)(Ap1 + ka);
            f16x8 a2 = *(const f16x8*)(Ap2 + ka);
            f16x8 a3 = *(const f16x8*)(Ap3 + ka);
            // hi batch: 4 LDS reads feed 16 MFMAs (per-acc hi-then-lo kept)
            f16x8 bh0 = *(const f16x8*)&Bs[buf][0][0 * 16 + l15][kl];
            f16x8 bh1 = *(const f16x8*)&Bs[buf][0][1 * 16 + l15][kl];
            f16x8 bh2 = *(const f16x8*)&Bs[buf][0][2 * 16 + l15][kl];
            f16x8 bh3 = *(const f16x8*)&Bs[buf][0][3 * 16 + l15][kl];
            acc00 = __builtin_amdgcn_mfma_f32_16x16x32_f16(a0, bh0, acc00, 0, 0, 0);
            acc10 = __builtin_amdgcn_mfma_f32_16x16x32_f16(a1, bh0, acc10, 0, 0, 0);
            acc20 = __builtin_amdgcn_mfma_f32_16x16x32_f16(a2, bh0, acc20, 0, 0, 0);
            acc30 = __builtin_amdgcn_mfma_f32_16x16x32_f16(a3, bh0, acc30, 0, 0, 0);
            acc01 = __builtin_amdgcn_mfma_f32_16x16x32_f16(a0, bh1, acc01, 0, 0, 0);
            acc11 = __builtin_amdgcn_mfma_f32_16x16x32_f16(a1, bh1, acc11, 0, 0, 0);
            acc21 = __builtin_amdgcn_mfma_f32_16x16x32_f16(a2, bh1, acc21, 0, 0, 0);
            acc31 = __builtin_amdgcn_mfma_f32_16x16x32_f16(a3, bh1, acc31, 0, 0, 0);
            acc02 = __builtin_amdgcn_mfma_f32_16x16x32_f16(a0, bh2, acc02, 0, 0, 0);
            acc12 = __builtin_amdgcn_mfma_f32_16x16x32_f16(a1, bh2, acc12, 0, 0, 0);
            acc22 = __builtin_amdgcn_mfma_f32_16x16x32_f16(a2, bh2, acc22, 0, 0, 0);
            acc32 = __builtin_amdgcn_mfma_f32_16x16x32_f16(a3, bh2, acc32, 0, 0, 0);
            acc03 = __builtin_amdgcn_mfma_f32_16x16x32_f16(a0, bh3, acc03, 0, 0, 0);
            acc13 = __builtin_amdgcn_mfma_f32_16x16x32_f16(a1, bh3, acc13, 0, 0, 0);
            acc23 = __builtin_amdgcn_mfma_f32_16x16x32_f16(a2, bh3, acc23, 0, 0, 0);
            acc33 = __builtin_amdgcn_mfma_f32_16x16x32_f16(a3, bh3, acc33, 0, 0, 0);
            // lo batch
            f16x8 bl0 = *(const f16x8*)&Bs[buf][1][0 * 16 + l15][kl];
            f16x8 bl1 = *(const f16x8*)&Bs[buf][1][1 * 16 + l15][kl];
            f16x8 bl2 = *(const f16x8*)&Bs[buf][1][2 * 16 + l15][kl];
            f16x8 bl3 = *(const f16x8*)&Bs[buf][1][3 * 16 + l15][kl];
            acc00 = __builtin_amdgcn_mfma_f32_16x16x32_f16(a0, bl0, acc00, 0, 0, 0);
            acc10 = __builtin_amdgcn_mfma_f32_16x16x32_f16(a1, bl0, acc10, 0, 0, 0);
            acc20 = __builtin_amdgcn_mfma_f32_16x16x32_f16(a2, bl0, acc20, 0, 0, 0);
            acc30 = __builtin_amdgcn_mfma_f32_16x16x32_f16(a3, bl0, acc30, 0, 0, 0);
            acc01 = __builtin_amdgcn_mfma_f32_16x16x32_f16(a0, bl1, acc01, 0, 0, 0);
            acc11 = __builtin_amdgcn_mfma_f32_16x16x32_f16(a1, bl1, acc11, 0, 0, 0);
            acc21 = __builtin_amdgcn_mfma_f32_16x16x32_f16(a2, bl1, acc21, 0, 0, 0);
            acc31 = __builtin_amdgcn_mfma_f32_16x16x32_f16(a3, bl1, acc31, 0, 0, 0);
            acc02 = __builtin_amdgcn_mfma_f32_16x16x32_f16(a0, bl2, acc02, 0, 0, 0);
            acc12 = __builtin_amdgcn_mfma_f32_16x16x32_f16(a1, bl2, acc12, 0, 0, 0);
            acc22 = __builtin_amdgcn_mfma_f32_16x16x32_f16(a2, bl2, acc22, 0, 0, 0);
            acc32 = __builtin_amdgcn_mfma_f32_16x16x32_f16(a3, bl2, acc32, 0, 0, 0);
            acc03 = __builtin_amdgcn_mfma_f32_16x16x32_f16(a0, bl3, acc03, 0, 0, 0);
            acc13 = __builtin_amdgcn_mfma_f32_16x16x32_f16(a1, bl3, acc13, 0, 0, 0);
            acc23 = __builtin_amdgcn_mfma_f32_16x16x32_f16(a2, bl3, acc23, 0, 0, 0);
            acc33 = __builtin_amdgcn_mfma_f32_16x16x32_f16(a3, bl3, acc33, 0, 0, 0);
        }
        if (sub < NSUB - 1) {
            const int nb = buf ^ 1;
            *(f16x8*)&Bs[nb][0][scol][spart]     = sh0;
            *(f16x8*)&Bs[nb][0][scol][spart + 8] = sh1;
            *(f16x8*)&Bs[nb][1][scol][spart]     = sl0;
            *(f16x8*)&Bs[nb][1][scol][spart + 8] = sl1;
            __syncthreads();
        }
    }
    float* Pp = P + ((long)ks * NQ + row0) * EMB;
#pragma unroll
    for (int i = 0; i < 4; ++i) {
        const int r = kg * 4 + i;
        Pp[r * EMB +  0 + l15] = acc00[i];
        Pp[r * EMB + 16 + l15] = acc01[i];
        Pp[r * EMB + 32 + l15] = acc02[i];
        Pp[r * EMB + 48 + l15] = acc03[i];
        Pp[(16 + r) * EMB +  0 + l15] = acc10[i];
        Pp[(16 + r) * EMB + 16 + l15] = acc11[i];
        Pp[(16 + r) * EMB + 32 + l15] = acc12[i];
        Pp[(16 + r) * EMB + 48 + l15] = acc13[i];
        Pp[(32 + r) * EMB +  0 + l15] = acc20[i];
        Pp[(32 + r) * EMB + 16 + l15] = acc21[i];
        Pp[(32 + r) * EMB + 32 + l15] = acc22[i];
        Pp[(32 + r) * EMB + 48 + l15] = acc23[i];
        Pp[(48 + r) * EMB +  0 + l15] = acc30[i];
        Pp[(48 + r) * EMB + 16 + l15] = acc31[i];
        Pp[(48 + r) * EMB + 32 + l15] = acc32[i];
        Pp[(48 + r) * EMB + 48 + l15] = acc33[i];
    }
}

// ---------------------------------------------------------------------------
// compensated bf16 matmul: acc += (Ahi+Alo) @ (Bhi+Blo)^T  (drop lo*lo)
__device__ __forceinline__ void mmstage3(const __bf16* Ah, const __bf16* Al,
                                         const __bf16* Bh, const __bf16* Bl,
                                         int rloc, int l15, int kg, f32x4 acc[4],
                                         bool init) {
    if (init) { acc[0] = {}; acc[1] = {}; acc[2] = {}; acc[3] = {}; }
#pragma unroll
    for (int kk = 0; kk < EMB; kk += 32) {
        const int ka = kk + kg * 8;
        const int aidx = (rloc * EMB + ka) ^ ((rloc & 7) << 3);
        bf16x8 ah = *(const bf16x8*)&Ah[aidx];
        bf16x8 al = *(const bf16x8*)&Al[aidx];
#pragma unroll
        for (int ct = 0; ct < 4; ++ct) {
            bf16x8 bh = *(const bf16x8*)&Bh[(ct * 16 + l15) * EMB + ka];
            bf16x8 bl = *(const bf16x8*)&Bl[(ct * 16 + l15) * EMB + ka];
            acc[ct] = __builtin_amdgcn_mfma_f32_16x16x32_bf16(ah, bh, acc[ct], 0, 0, 0);
            acc[ct] = __builtin_amdgcn_mfma_f32_16x16x32_bf16(ah, bl, acc[ct], 0, 0, 0);
            acc[ct] = __builtin_amdgcn_mfma_f32_16x16x32_bf16(al, bh, acc[ct], 0, 0, 0);
        }
    }
}

// reduce partials -> mlpV (relu) -> RNN tanh -> V (fp32) + Vt (fp16 hi/lo ^T)
// 512 blocks x 256 threads x 16 nodes = 8 waves/CU for the P reduction;
// wave 0 runs the (tiny) MFMA stages.
#define SNODE 16
__global__ __launch_bounds__(256, 2) void k_step(
    const float* __restrict__ P, const float* Hprev,
    const float* __restrict__ b1, const float* __restrict__ b2,
    const float* __restrict__ bih, const float* __restrict__ bhh,
    const __bf16* __restrict__ w1h, const __bf16* __restrict__ w1l,
    const __bf16* __restrict__ w2h, const __bf16* __restrict__ w2l,
    const __bf16* __restrict__ wihH, const __bf16* __restrict__ wihL,
    const __bf16* __restrict__ whhH, const __bf16* __restrict__ whhL,
    float* Vout, _Float16* __restrict__ Vth, _Float16* __restrict__ Vtl,
    int isFirst) {
    __shared__ __bf16 Ahi[SNODE * EMB], Alo[SNODE * EMB];
    __shared__ __bf16 Phi[SNODE * EMB], Plo[SNODE * EMB];
    __shared__ __bf16 Hhi[SNODE * EMB], Hlo[SNODE * EMB];
    __shared__ __bf16 Xhi[SNODE * EMB], Xlo[SNODE * EMB];
    const int t = threadIdx.x;
    const int base = blockIdx.x * SNODE;

    // float4 reduction over KSPLIT partials (identical add order per element)
    for (int i = t * 4; i < SNODE * EMB; i += 256 * 4) {
        const int node = i >> 6, col = i & 63;
        float4 s = {0.f, 0.f, 0.f, 0.f};
#pragma unroll
        for (int sp = 0; sp < KSPLIT; ++sp) {
            float4 pv = *(const float4*)&P[((long)sp * NQ + base + node) * EMB + col];
            s.x += pv.x; s.y += pv.y; s.z += pv.z; s.w += pv.w;
        }
        float4 hp = {0.f, 0.f, 0.f, 0.f};
        if (!isFirst) hp = *(const float4*)&Hprev[(long)(base + node) * EMB + col];
        const float sv[4] = {s.x * MINV, s.y * MINV, s.z * MINV, s.w * MINV};
        const float hv[4] = {hp.x, hp.y, hp.z, hp.w};
#pragma unroll
        for (int j = 0; j < 4; ++j) {
            const int sw = (i + j) ^ ((node & 7) << 3);
            __bf16 hi = (__bf16)sv[j];
            Ahi[sw] = hi; Alo[sw] = (__bf16)(sv[j] - (float)hi);
            hi = (__bf16)hv[j];
            Phi[sw] = hi; Plo[sw] = (__bf16)(hv[j] - (float)hi);
        }
    }
    __syncthreads();

    const int wave = t >> 6, lane = t & 63, l15 = lane & 15, kg = lane >> 4;
    const int rloc = l15;   // wave 0 only: 16 rows
    f32x4 acc[4];

    // mm1: h1 = relu(agg @ w1 + b1)
    if (wave == 0) {
        mmstage3(Ahi, Alo, w1h, w1l, rloc, l15, kg, acc, true);
#pragma unroll
        for (int ct = 0; ct < 4; ++ct) {
            const int c = ct * 16 + l15;
            const float bc = b1[c];
#pragma unroll
            for (int i = 0; i < 4; ++i) {
                const int r = kg * 4 + i;
                const float v = fmaxf(acc[ct][i] + bc, 0.f);
                const int sw = (r * EMB + c) ^ ((r & 7) << 3);
                __bf16 hi = (__bf16)v;
                Hhi[sw] = hi; Hlo[sw] = (__bf16)(v - (float)hi);
            }
        }
    }
    __syncthreads();

    // mm2: x = h1 @ w2 + b2
    if (wave == 0) {
        mmstage3(Hhi, Hlo, w2h, w2l, rloc, l15, kg, acc, true);
#pragma unroll
        for (int ct = 0; ct < 4; ++ct) {
            const int c = ct * 16 + l15;
            const float bc = b2[c];
#pragma unroll
            for (int i = 0; i < 4; ++i) {
                const int r = kg * 4 + i;
                const float v = acc[ct][i] + bc;
                const int sw = (r * EMB + c) ^ ((r & 7) << 3);
                __bf16 hi = (__bf16)v;
                Xhi[sw] = hi; Xlo[sw] = (__bf16)(v - (float)hi);
            }
        }
    }
    __syncthreads();

    // rnn: h_new = tanh(x @ wih^T + h @ whh^T + bih + bhh)
    if (wave == 0) {
        mmstage3(Xhi, Xlo, wihH, wihL, rloc, l15, kg, acc, true);
        mmstage3(Phi, Plo, whhH, whhL, rloc, l15, kg, acc, false);
#pragma unroll
        for (int ct = 0; ct < 4; ++ct) {
            const int c = ct * 16 + l15;
            const float bc = bih[c] + bhh[c];
#pragma unroll
            for (int i = 0; i < 4; ++i) {
                const int r = kg * 4 + i;
                const float v = tanhf(acc[ct][i] + bc);
                Vout[(long)(base + r) * EMB + c] = v;
                const _Float16 hi = (_Float16)v;
                Vth[(long)c * NQ + base + r] = hi;
                Vtl[(long)c * NQ + base + r] = (_Float16)(v - (float)hi);
            }
        }
    }
}

// ---------------------------------------------------------------------------
// vote MLP + per-graph mean + sigmoid. block = one graph (256 nodes)
__global__ __launch_bounds__(256) void k_vote(const float* __restrict__ V,
                                              const float* __restrict__ vw1,
                                              const float* __restrict__ vb1,
                                              const float* __restrict__ vw2,
                                              const float* __restrict__ vb2,
                                              float* __restrict__ out) {
    __shared__ float W1[EMB * EMB];
    __shared__ float red[256];
    const int g = blockIdx.x, t = threadIdx.x;
    for (int i = t; i < EMB * EMB; i += 256) W1[i] = vw1[i];
    __syncthreads();
    const int node = g * 256 + t;
    float a[EMB];
    const float4* vp4 = (const float4*)(V + (long)node * EMB);
#pragma unroll
    for (int k = 0; k < 16; ++k) {
        float4 f = vp4[k];
        a[4 * k] = f.x; a[4 * k + 1] = f.y; a[4 * k + 2] = f.z; a[4 * k + 3] = f.w;
    }
    float vote = vb2[0];
    for (int j = 0; j < EMB; ++j) {
        float h = vb1[j];
#pragma unroll
        for (int k = 0; k < EMB; ++k) h += a[k] * W1[k * EMB + j];
        vote += fmaxf(h, 0.f) * vw2[j];
    }
    red[t] = vote;
    __syncthreads();
    for (int s = 128; s > 0; s >>= 1) {
        if (t < s) red[t] += red[t + s];
        __syncthreads();
    }
    if (t == 0) {
        const float mean = red[0] / 256.f;
        out[g] = 1.f / (1.f + expf(-mean));
        out[32 + g] = mean;
    }
}

// ---------------------------------------------------------------------------
extern "C" void kernel_launch(void* const* d_in, const int* in_sizes, int n_in,
                              void* d_out, int out_size, void* d_ws, size_t ws_size,
                              hipStream_t stream) {
    const float* M     = (const float*)d_in[0];
    const float* vi_w1 = (const float*)d_in[2];
    const float* vi_b1 = (const float*)d_in[3];
    const float* vi_w2 = (const float*)d_in[4];
    const float* vi_b2 = (const float*)d_in[5];
    const float* m_w1  = (const float*)d_in[6];
    const float* m_b1  = (const float*)d_in[7];
    const float* m_w2  = (const float*)d_in[8];
    const float* m_b2  = (const float*)d_in[9];
    const float* r_wih = (const float*)d_in[10];
    const float* r_whh = (const float*)d_in[11];
    const float* r_bih = (const float*)d_in[12];
    const float* r_bhh = (const float*)d_in[13];
    const float* v_w1  = (const float*)d_in[14];
    const float* v_b1  = (const float*)d_in[15];
    const float* v_w2  = (const float*)d_in[16];
    const float* v_b2  = (const float*)d_in[17];

    float* out  = (float*)d_out;
    float* Vout = out + 64;   // [8192][64] fp32, also serves as h_prev

    char* p = (char*)d_ws;
    _Float16* Mh  = (_Float16*)p; p += (size_t)NQ * NQ * 2;
    float*    part = (float*)p;   p += (size_t)KSPLIT * NQ * EMB * 4;
    _Float16* Vth = (_Float16*)p; p += (size_t)EMB * NQ * 2;
    _Float16* Vtl = (_Float16*)p; p += (size_t)EMB * NQ * 2;
    __bf16* w1h  = (__bf16*)p; p += EMB * EMB * 2;
    __bf16* w1l  = (__bf16*)p; p += EMB * EMB * 2;
    __bf16* w2h  = (__bf16*)p; p += EMB * EMB * 2;
    __bf16* w2l  = (__bf16*)p; p += EMB * EMB * 2;
    __bf16* wihH = (__bf16*)p; p += EMB * EMB * 2;
    __bf16* wihL = (__bf16*)p; p += EMB * EMB * 2;
    __bf16* whhH = (__bf16*)p; p += EMB * EMB * 2;
    __bf16* whhL = (__bf16*)p; p += EMB * EMB * 2;
    float*  v0   = (float*)p;  p += EMB * 4;

    hipLaunchKernelGGL(k_conv, dim3(4096), dim3(256), 0, stream, M, Mh, (long)NQ * NQ);
    hipLaunchKernelGGL(k_wprep, dim3(1), dim3(256), 0, stream, vi_w1, vi_b1, vi_w2, vi_b2,
                       m_w1, m_w2, r_wih, r_whh, v0, w1h, w1l, w2h, w2l,
                       wihH, wihL, whhH, whhL);
    hipLaunchKernelGGL(k_fill, dim3(EMB), dim3(256), 0, stream, v0, Vth, Vtl);

    for (int t = 0; t < TMAX; ++t) {
        hipLaunchKernelGGL(k_gemm_big, dim3((NQ / 256) * KSPLIT), dim3(256), 0, stream,
                           Mh, Vth, Vtl, part);
        hipLaunchKernelGGL(k_step, dim3(NQ / SNODE), dim3(256), 0, stream, part, Vout,
                           m_b1, m_b2, r_bih, r_bhh, w1h, w1l, w2h, w2l,
                           wihH, wihL, whhH, whhL, Vout, Vth, Vtl,
                           t == 0 ? 1 : 0);
    }
    hipLaunchKernelGGL(k_vote, dim3(32), dim3(256), 0, stream, Vout, v_w1, v_b1, v_w2,
                       v_b2, out);
}

// Round 10
// 1495.827 us; speedup vs baseline: 1.2774x; 1.2774x over previous
//
#include <hip/hip_runtime.h>
#include <hip/hip_bf16.h>
#include <cmath>

#define NQ 8192
#define EMB 64
#define KSPLIT 16
#define KCHUNK (NQ / KSPLIT)
#define TMAX 32
#define MSCALE 256.0f
#define MINV (1.0f / 256.0f)
#define SUBK 64
#define BPAD 72
#define NSUB (KCHUNK / SUBK)

typedef __bf16 bf16x8 __attribute__((ext_vector_type(8)));
typedef _Float16 f16x8 __attribute__((ext_vector_type(8)));
typedef float f32x4 __attribute__((ext_vector_type(4)));

// ---------------------------------------------------------------------------
// M fp32 -> fp16 (scaled by 256 to stay clear of fp16 subnormals)
__global__ __launch_bounds__(256) void k_conv(const float* __restrict__ M,
                                              _Float16* __restrict__ Mh, long n) {
    long i = ((long)blockIdx.x * 256 + threadIdx.x) * 8;
    const long stride = (long)gridDim.x * 256 * 8;
    for (; i < n; i += stride) {
        float4 f0 = *(const float4*)(M + i);
        float4 f1 = *(const float4*)(M + i + 4);
        f16x8 o;
        o[0] = (_Float16)(f0.x * MSCALE); o[1] = (_Float16)(f0.y * MSCALE);
        o[2] = (_Float16)(f0.z * MSCALE); o[3] = (_Float16)(f0.w * MSCALE);
        o[4] = (_Float16)(f1.x * MSCALE); o[5] = (_Float16)(f1.y * MSCALE);
        o[6] = (_Float16)(f1.z * MSCALE); o[7] = (_Float16)(f1.w * MSCALE);
        *(f16x8*)(Mh + i) = o;
    }
}

// ---------------------------------------------------------------------------
// v0 + hi/lo bf16 weight prep (B^T layouts)
__global__ __launch_bounds__(256) void k_wprep(
    const float* __restrict__ vi_w1, const float* __restrict__ vi_b1,
    const float* __restrict__ vi_w2, const float* __restrict__ vi_b2,
    const float* __restrict__ w1, const float* __restrict__ w2,
    const float* __restrict__ wih, const float* __restrict__ whh,
    float* __restrict__ v0,
    __bf16* __restrict__ w1h, __bf16* __restrict__ w1l,
    __bf16* __restrict__ w2h, __bf16* __restrict__ w2l,
    __bf16* __restrict__ wihH, __bf16* __restrict__ wihL,
    __bf16* __restrict__ whhH, __bf16* __restrict__ whhL) {
    __shared__ float h[EMB];
    const int t = threadIdx.x;
    if (t < EMB) h[t] = vi_w1[t] + vi_b1[t];
    __syncthreads();
    if (t < EMB) {
        float s = vi_b2[t];
        for (int i = 0; i < EMB; ++i) s += h[i] * vi_w2[i * EMB + t];
        v0[t] = s;
    }
    for (int i = t; i < EMB * EMB; i += 256) {
        const int r = i >> 6, c = i & 63;     // target [r][c] = B[out][k]
        float v;
        __bf16 hi;
        v = w1[c * EMB + r]; hi = (__bf16)v;                 // w1t[j][k]=w1[k][j]
        w1h[i] = hi; w1l[i] = (__bf16)(v - (float)hi);
        v = w2[c * EMB + r]; hi = (__bf16)v;
        w2h[i] = hi; w2l[i] = (__bf16)(v - (float)hi);
        v = wih[i]; hi = (__bf16)v;                          // (x@wih^T): B=wih
        wihH[i] = hi; wihL[i] = (__bf16)(v - (float)hi);
        v = whh[i]; hi = (__bf16)v;
        whhH[i] = hi; whhL[i] = (__bf16)(v - (float)hi);
    }
}

// Vt hi/lo [c][k] = fp16 split of v0[c]
__global__ __launch_bounds__(256) void k_fill(const float* __restrict__ v0,
                                              _Float16* __restrict__ Vh,
                                              _Float16* __restrict__ Vl) {
    const int c = blockIdx.x;
    const float v = v0[c];
    const _Float16 hi = (_Float16)v;
    const _Float16 lo = (_Float16)(v - (float)hi);
    f16x8 oh = {hi, hi, hi, hi, hi, hi, hi, hi};
    f16x8 ol = {lo, lo, lo, lo, lo, lo, lo, lo};
    for (int i = threadIdx.x; i < NQ / 8; i += 256) {
        *(f16x8*)(Vh + (long)c * NQ + (long)i * 8) = oh;
        *(f16x8*)(Vl + (long)c * NQ + (long)i * 8) = ol;
    }
}

// ---------------------------------------------------------------------------
// partials[ks][row][col] = sum_{k chunk} Mh[row][k] * (Vh+Vl)[col][k]
// R8 structure (32 rows/wave, 128 rows/block, 4 blocks/CU, LDS-staged B,
// A-prefetch) + XCD-aware ks placement: blocks land on XCDs round-robin
// (XCD = bid % 8), so map ks = (bid%8)*2 + ((bid>>3)&1) -> each XCD owns
// exactly 2 B ks-slices (256 KB, L2-resident) instead of scattering all 16
// across XCDs. B re-fetch (128 MB/launch) moves from L3 to L2. Perf-only:
// block->tile mapping is bijective, per-tile arithmetic unchanged.
__global__ __launch_bounds__(256, 4) void k_gemm_big(
    const _Float16* __restrict__ A, const _Float16* __restrict__ Bh,
    const _Float16* __restrict__ Bl, float* __restrict__ P) {
    __shared__ _Float16 Bs[2][2][EMB][BPAD];
    const int hb   = blockIdx.x;
    const int r16  = hb & 15;
    const int ks   = ((r16 & 7) << 1) | (r16 >> 3);
    const int rt   = hb >> 4;
    const int t    = threadIdx.x;
    const int wave = t >> 6;
    const int lane = t & 63;
    const int l15  = lane & 15;
    const int kg   = lane >> 4;
    const int row0 = rt * 128 + wave * 32;
    const long kcb = (long)ks * KCHUNK;
    const _Float16* Ap0 = A + (long)(row0 + l15) * NQ + kcb + kg * 8;
    const _Float16* Ap1 = Ap0 + (long)16 * NQ;
    // staging: thread t covers col=t/4, k-window (t%4)*16 .. +16 of each subchunk
    const int scol  = t >> 2;
    const int spart = (t & 3) * 16;
    const _Float16* gH = Bh + (long)scol * NQ + kcb + spart;
    const _Float16* gL = Bl + (long)scol * NQ + kcb + spart;

    f32x4 acc00 = {}, acc01 = {}, acc02 = {}, acc03 = {};
    f32x4 acc10 = {}, acc11 = {}, acc12 = {}, acc13 = {};

    // prologue: stage subchunk 0 into buf 0, load subchunk 0's A fragments
    f16x8 sh0 = *(const f16x8*)(gH);
    f16x8 sh1 = *(const f16x8*)(gH + 8);
    f16x8 sl0 = *(const f16x8*)(gL);
    f16x8 sl1 = *(const f16x8*)(gL + 8);
    f16x8 a00 = *(const f16x8*)(Ap0);        // iter0 rows 0-15
    f16x8 a10 = *(const f16x8*)(Ap1);        // iter0 rows 16-31
    f16x8 a01 = *(const f16x8*)(Ap0 + 32);   // iter1
    f16x8 a11 = *(const f16x8*)(Ap1 + 32);
    *(f16x8*)&Bs[0][0][scol][spart]     = sh0;
    *(f16x8*)&Bs[0][0][scol][spart + 8] = sh1;
    *(f16x8*)&Bs[0][1][scol][spart]     = sl0;
    *(f16x8*)&Bs[0][1][scol][spart + 8] = sl1;
    __syncthreads();

#pragma unroll
    for (int sub = 0; sub < NSUB; ++sub) {
        const int buf = sub & 1;
        f16x8 na00, na10, na01, na11;
        // prefetch next subchunk: B (global->reg, LDS-written after compute)
        // then A (global->reg, consumed after the next barrier)
        if (sub < NSUB - 1) {
            const long nk = (long)(sub + 1) * SUBK;
            sh0 = *(const f16x8*)(gH + nk);
            sh1 = *(const f16x8*)(gH + nk + 8);
            sl0 = *(const f16x8*)(gL + nk);
            sl1 = *(const f16x8*)(gL + nk + 8);
            na00 = *(const f16x8*)(Ap0 + nk);
            na10 = *(const f16x8*)(Ap1 + nk);
            na01 = *(const f16x8*)(Ap0 + nk + 32);
            na11 = *(const f16x8*)(Ap1 + nk + 32);
        }
#pragma unroll
        for (int it = 0; it < 2; ++it) {      // 2 iters of k=32
            const int kl = it * 32 + kg * 8;
            const f16x8 a0 = it ? a01 : a00;
            const f16x8 a1 = it ? a11 : a10;
            // hi batch: read 4 frags, 8 MFMAs (per-acc order hi-then-lo kept)
            f16x8 bh0 = *(const f16x8*)&Bs[buf][0][0 * 16 + l15][kl];
            f16x8 bh1 = *(const f16x8*)&Bs[buf][0][1 * 16 + l15][kl];
            f16x8 bh2 = *(const f16x8*)&Bs[buf][0][2 * 16 + l15][kl];
            f16x8 bh3 = *(const f16x8*)&Bs[buf][0][3 * 16 + l15][kl];
            acc00 = __builtin_amdgcn_mfma_f32_16x16x32_f16(a0, bh0, acc00, 0, 0, 0);
            acc10 = __builtin_amdgcn_mfma_f32_16x16x32_f16(a1, bh0, acc10, 0, 0, 0);
            acc01 = __builtin_amdgcn_mfma_f32_16x16x32_f16(a0, bh1, acc01, 0, 0, 0);
            acc11 = __builtin_amdgcn_mfma_f32_16x16x32_f16(a1, bh1, acc11, 0, 0, 0);
            acc02 = __builtin_amdgcn_mfma_f32_16x16x32_f16(a0, bh2, acc02, 0, 0, 0);
            acc12 = __builtin_amdgcn_mfma_f32_16x16x32_f16(a1, bh2, acc12, 0, 0, 0);
            acc03 = __builtin_amdgcn_mfma_f32_16x16x32_f16(a0, bh3, acc03, 0, 0, 0);
            acc13 = __builtin_amdgcn_mfma_f32_16x16x32_f16(a1, bh3, acc13, 0, 0, 0);
            // lo batch
            f16x8 bl0 = *(const f16x8*)&Bs[buf][1][0 * 16 + l15][kl];
            f16x8 bl1 = *(const f16x8*)&Bs[buf][1][1 * 16 + l15][kl];
            f16x8 bl2 = *(const f16x8*)&Bs[buf][1][2 * 16 + l15][kl];
            f16x8 bl3 = *(const f16x8*)&Bs[buf][1][3 * 16 + l15][kl];
            acc00 = __builtin_amdgcn_mfma_f32_16x16x32_f16(a0, bl0, acc00, 0, 0, 0);
            acc10 = __builtin_amdgcn_mfma_f32_16x16x32_f16(a1, bl0, acc10, 0, 0, 0);
            acc01 = __builtin_amdgcn_mfma_f32_16x16x32_f16(a0, bl1, acc01, 0, 0, 0);
            acc11 = __builtin_amdgcn_mfma_f32_16x16x32_f16(a1, bl1, acc11, 0, 0, 0);
            acc02 = __builtin_amdgcn_mfma_f32_16x16x32_f16(a0, bl2, acc02, 0, 0, 0);
            acc12 = __builtin_amdgcn_mfma_f32_16x16x32_f16(a1, bl2, acc12, 0, 0, 0);
            acc03 = __builtin_amdgcn_mfma_f32_16x16x32_f16(a0, bl3, acc03, 0, 0, 0);
            acc13 = __builtin_amdgcn_mfma_f32_16x16x32_f16(a1, bl3, acc13, 0, 0, 0);
        }
        if (sub < NSUB - 1) {
            const int nb = buf ^ 1;
            *(f16x8*)&Bs[nb][0][scol][spart]     = sh0;
            *(f16x8*)&Bs[nb][0][scol][spart + 8] = sh1;
            *(f16x8*)&Bs[nb][1][scol][spart]     = sl0;
            *(f16x8*)&Bs[nb][1][scol][spart + 8] = sl1;
            __syncthreads();
            a00 = na00; a10 = na10; a01 = na01; a11 = na11;
        }
    }
    float* Pp = P + ((long)ks * NQ + row0) * EMB;
#pragma unroll
    for (int i = 0; i < 4; ++i) {
        const int r = kg * 4 + i;
        Pp[r * EMB +  0 + l15] = acc00[i];
        Pp[r * EMB + 16 + l15] = acc01[i];
        Pp[r * EMB + 32 + l15] = acc02[i];
        Pp[r * EMB + 48 + l15] = acc03[i];
        Pp[(16 + r) * EMB +  0 + l15] = acc10[i];
        Pp[(16 + r) * EMB + 16 + l15] = acc11[i];
        Pp[(16 + r) * EMB + 32 + l15] = acc12[i];
        Pp[(16 + r) * EMB + 48 + l15] = acc13[i];
    }
}

// ---------------------------------------------------------------------------
// compensated bf16 matmul: acc += (Ahi+Alo) @ (Bhi+Blo)^T  (drop lo*lo)
__device__ __forceinline__ void mmstage3(const __bf16* Ah, const __bf16* Al,
                                         const __bf16* Bh, const __bf16* Bl,
                                         int rloc, int l15, int kg, f32x4 acc[4],
                                         bool init) {
    if (init) { acc[0] = {}; acc[1] = {}; acc[2] = {}; acc[3] = {}; }
#pragma unroll
    for (int kk = 0; kk < EMB; kk += 32) {
        const int ka = kk + kg * 8;
        const int aidx = (rloc * EMB + ka) ^ ((rloc & 7) << 3);
        bf16x8 ah = *(const bf16x8*)&Ah[aidx];
        bf16x8 al = *(const bf16x8*)&Al[aidx];
#pragma unroll
        for (int ct = 0; ct < 4; ++ct) {
            bf16x8 bh = *(const bf16x8*)&Bh[(ct * 16 + l15) * EMB + ka];
            bf16x8 bl = *(const bf16x8*)&Bl[(ct * 16 + l15) * EMB + ka];
            acc[ct] = __builtin_amdgcn_mfma_f32_16x16x32_bf16(ah, bh, acc[ct], 0, 0, 0);
            acc[ct] = __builtin_amdgcn_mfma_f32_16x16x32_bf16(ah, bl, acc[ct], 0, 0, 0);
            acc[ct] = __builtin_amdgcn_mfma_f32_16x16x32_bf16(al, bh, acc[ct], 0, 0, 0);
        }
    }
}

// reduce partials -> mlpV (relu) -> RNN tanh -> V (fp32) + Vt (fp16 hi/lo ^T)
// 512 blocks x 256 threads x 16 nodes = 8 waves/CU for the P reduction;
// wave 0 runs the (tiny) MFMA stages.
#define SNODE 16
__global__ __launch_bounds__(256, 2) void k_step(
    const float* __restrict__ P, const float* Hprev,
    const float* __restrict__ b1, const float* __restrict__ b2,
    const float* __restrict__ bih, const float* __restrict__ bhh,
    const __bf16* __restrict__ w1h, const __bf16* __restrict__ w1l,
    const __bf16* __restrict__ w2h, const __bf16* __restrict__ w2l,
    const __bf16* __restrict__ wihH, const __bf16* __restrict__ wihL,
    const __bf16* __restrict__ whhH, const __bf16* __restrict__ whhL,
    float* Vout, _Float16* __restrict__ Vth, _Float16* __restrict__ Vtl,
    int isFirst) {
    __shared__ __bf16 Ahi[SNODE * EMB], Alo[SNODE * EMB];
    __shared__ __bf16 Phi[SNODE * EMB], Plo[SNODE * EMB];
    __shared__ __bf16 Hhi[SNODE * EMB], Hlo[SNODE * EMB];
    __shared__ __bf16 Xhi[SNODE * EMB], Xlo[SNODE * EMB];
    const int t = threadIdx.x;
    const int base = blockIdx.x * SNODE;

    // float4 reduction over KSPLIT partials (identical add order per element)
    for (int i = t * 4; i < SNODE * EMB; i += 256 * 4) {
        const int node = i >> 6, col = i & 63;
        float4 s = {0.f, 0.f, 0.f, 0.f};
#pragma unroll
        for (int sp = 0; sp < KSPLIT; ++sp) {
            float4 pv = *(const float4*)&P[((long)sp * NQ + base + node) * EMB + col];
            s.x += pv.x; s.y += pv.y; s.z += pv.z; s.w += pv.w;
        }
        float4 hp = {0.f, 0.f, 0.f, 0.f};
        if (!isFirst) hp = *(const float4*)&Hprev[(long)(base + node) * EMB + col];
        const float sv[4] = {s.x * MINV, s.y * MINV, s.z * MINV, s.w * MINV};
        const float hv[4] = {hp.x, hp.y, hp.z, hp.w};
#pragma unroll
        for (int j = 0; j < 4; ++j) {
            const int sw = (i + j) ^ ((node & 7) << 3);
            __bf16 hi = (__bf16)sv[j];
            Ahi[sw] = hi; Alo[sw] = (__bf16)(sv[j] - (float)hi);
            hi = (__bf16)hv[j];
            Phi[sw] = hi; Plo[sw] = (__bf16)(hv[j] - (float)hi);
        }
    }
    __syncthreads();

    const int wave = t >> 6, lane = t & 63, l15 = lane & 15, kg = lane >> 4;
    const int rloc = l15;   // wave 0 only: 16 rows
    f32x4 acc[4];

    // mm1: h1 = relu(agg @ w1 + b1)
    if (wave == 0) {
        mmstage3(Ahi, Alo, w1h, w1l, rloc, l15, kg, acc, true);
#pragma unroll
        for (int ct = 0; ct < 4; ++ct) {
            const int c = ct * 16 + l15;
            const float bc = b1[c];
#pragma unroll
            for (int i = 0; i < 4; ++i) {
                const int r = kg * 4 + i;
                const float v = fmaxf(acc[ct][i] + bc, 0.f);
                const int sw = (r * EMB + c) ^ ((r & 7) << 3);
                __bf16 hi = (__bf16)v;
                Hhi[sw] = hi; Hlo[sw] = (__bf16)(v - (float)hi);
            }
        }
    }
    __syncthreads();

    // mm2: x = h1 @ w2 + b2
    if (wave == 0) {
        mmstage3(Hhi, Hlo, w2h, w2l, rloc, l15, kg, acc, true);
#pragma unroll
        for (int ct = 0; ct < 4; ++ct) {
            const int c = ct * 16 + l15;
            const float bc = b2[c];
#pragma unroll
            for (int i = 0; i < 4; ++i) {
                const int r = kg * 4 + i;
                const float v = acc[ct][i] + bc;
                const int sw = (r * EMB + c) ^ ((r & 7) << 3);
                __bf16 hi = (__bf16)v;
                Xhi[sw] = hi; Xlo[sw] = (__bf16)(v - (float)hi);
            }
        }
    }
    __syncthreads();

    // rnn: h_new = tanh(x @ wih^T + h @ whh^T + bih + bhh)
    if (wave == 0) {
        mmstage3(Xhi, Xlo, wihH, wihL, rloc, l15, kg, acc, true);
        mmstage3(Phi, Plo, whhH, whhL, rloc, l15, kg, acc, false);
#pragma unroll
        for (int ct = 0; ct < 4; ++ct) {
            const int c = ct * 16 + l15;
            const float bc = bih[c] + bhh[c];
#pragma unroll
            for (int i = 0; i < 4; ++i) {
                const int r = kg * 4 + i;
                const float v = tanhf(acc[ct][i] + bc);
                Vout[(long)(base + r) * EMB + c] = v;
                const _Float16 hi = (_Float16)v;
                Vth[(long)c * NQ + base + r] = hi;
                Vtl[(long)c * NQ + base + r] = (_Float16)(v - (float)hi);
            }
        }
    }
}

// ---------------------------------------------------------------------------
// vote MLP + per-graph mean + sigmoid. block = one graph (256 nodes)
__global__ __launch_bounds__(256) void k_vote(const float* __restrict__ V,
                                              const float* __restrict__ vw1,
                                              const float* __restrict__ vb1,
                                              const float* __restrict__ vw2,
                                              const float* __restrict__ vb2,
                                              float* __restrict__ out) {
    __shared__ float W1[EMB * EMB];
    __shared__ float red[256];
    const int g = blockIdx.x, t = threadIdx.x;
    for (int i = t; i < EMB * EMB; i += 256) W1[i] = vw1[i];
    __syncthreads();
    const int node = g * 256 + t;
    float a[EMB];
    const float4* vp4 = (const float4*)(V + (long)node * EMB);
#pragma unroll
    for (int k = 0; k < 16; ++k) {
        float4 f = vp4[k];
        a[4 * k] = f.x; a[4 * k + 1] = f.y; a[4 * k + 2] = f.z; a[4 * k + 3] = f.w;
    }
    float vote = vb2[0];
    for (int j = 0; j < EMB; ++j) {
        float h = vb1[j];
#pragma unroll
        for (int k = 0; k < EMB; ++k) h += a[k] * W1[k * EMB + j];
        vote += fmaxf(h, 0.f) * vw2[j];
    }
    red[t] = vote;
    __syncthreads();
    for (int s = 128; s > 0; s >>= 1) {
        if (t < s) red[t] += red[t + s];
        __syncthreads();
    }
    if (t == 0) {
        const float mean = red[0] / 256.f;
        out[g] = 1.f / (1.f + expf(-mean));
        out[32 + g] = mean;
    }
}

// ---------------------------------------------------------------------------
extern "C" void kernel_launch(void* const* d_in, const int* in_sizes, int n_in,
                              void* d_out, int out_size, void* d_ws, size_t ws_size,
                              hipStream_t stream) {
    const float* M     = (const float*)d_in[0];
    const float* vi_w1 = (const float*)d_in[2];
    const float* vi_b1 = (const float*)d_in[3];
    const float* vi_w2 = (const float*)d_in[4];
    const float* vi_b2 = (const float*)d_in[5];
    const float* m_w1  = (const float*)d_in[6];
    const float* m_b1  = (const float*)d_in[7];
    const float* m_w2  = (const float*)d_in[8];
    const float* m_b2  = (const float*)d_in[9];
    const float* r_wih = (const float*)d_in[10];
    const float* r_whh = (const float*)d_in[11];
    const float* r_bih = (const float*)d_in[12];
    const float* r_bhh = (const float*)d_in[13];
    const float* v_w1  = (const float*)d_in[14];
    const float* v_b1  = (const float*)d_in[15];
    const float* v_w2  = (const float*)d_in[16];
    const float* v_b2  = (const float*)d_in[17];

    float* out  = (float*)d_out;
    float* Vout = out + 64;   // [8192][64] fp32, also serves as h_prev

    char* p = (char*)d_ws;
    _Float16* Mh  = (_Float16*)p; p += (size_t)NQ * NQ * 2;
    float*    part = (float*)p;   p += (size_t)KSPLIT * NQ * EMB * 4;
    _Float16* Vth = (_Float16*)p; p += (size_t)EMB * NQ * 2;
    _Float16* Vtl = (_Float16*)p; p += (size_t)EMB * NQ * 2;
    __bf16* w1h  = (__bf16*)p; p += EMB * EMB * 2;
    __bf16* w1l  = (__bf16*)p; p += EMB * EMB * 2;
    __bf16* w2h  = (__bf16*)p; p += EMB * EMB * 2;
    __bf16* w2l  = (__bf16*)p; p += EMB * EMB * 2;
    __bf16* wihH = (__bf16*)p; p += EMB * EMB * 2;
    __bf16* wihL = (__bf16*)p; p += EMB * EMB * 2;
    __bf16* whhH = (__bf16*)p; p += EMB * EMB * 2;
    __bf16* whhL = (__bf16*)p; p += EMB * EMB * 2;
    float*  v0   = (float*)p;  p += EMB * 4;

    hipLaunchKernelGGL(k_conv, dim3(4096), dim3(256), 0, stream, M, Mh, (long)NQ * NQ);
    hipLaunchKernelGGL(k_wprep, dim3(1), dim3(256), 0, stream, vi_w1, vi_b1, vi_w2, vi_b2,
                       m_w1, m_w2, r_wih, r_whh, v0, w1h, w1l, w2h, w2l,
                       wihH, wihL, whhH, whhL);
    hipLaunchKernelGGL(k_fill, dim3(EMB), dim3(256), 0, stream, v0, Vth, Vtl);

    for (int t = 0; t < TMAX; ++t) {
        hipLaunchKernelGGL(k_gemm_big, dim3((NQ / 128) * KSPLIT), dim3(256), 0, stream,
                           Mh, Vth, Vtl, part);
        hipLaunchKernelGGL(k_step, dim3(NQ / SNODE), dim3(256), 0, stream, part, Vout,
                           m_b1, m_b2, r_bih, r_bhh, w1h, w1l, w2h, w2l,
                           wihH, wihL, whhH, whhL, Vout, Vth, Vtl,
                           t == 0 ? 1 : 0);
    }
    hipLaunchKernelGGL(k_vote, dim3(32), dim3(256), 0, stream, Vout, v_w1, v_b1, v_w2,
                       v_b2, out);
}